// Round 4
// baseline (112.614 us; speedup 1.0000x reference)
//
#include <hip/hip_runtime.h>
#include <hip/hip_cooperative_groups.h>

namespace cg = cooperative_groups;

// PointCloudRenderer — single cooperative kernel: zero -> scatter -> composite.
// RADIUS=0.005 NDC = 0.32 px < 0.5 px => each point covers AT MOST ONE pixel
// center (validated: rounds 2/3 passed with absmax 0.0). Scatter each point to
// its unique candidate pixel (global atomic append of {z,d2,idx}), grid-sync,
// then one thread per pixel insertion-sorts its tiny candidate list by
// lexicographic (z, point_idx) — reproducing top_k's deterministic tie-break
// regardless of atomic arrival order — and alpha-composites.

constexpr int   IMGC  = 128;
constexpr int   HWC   = IMGC * IMGC;
constexpr int   KTOP  = 10;
constexpr int   CAP   = 16;            // per-pixel candidate cap (peak density ~0.5/px)
constexpr float BIGF  = 1e10f;
constexpr float R2C   = 2.5e-05f;      // float32(0.005^2)
constexpr float SCALE = 0.015625f;     // 2/128, exact power of two

__launch_bounds__(256)
__global__ void fused_coop_kernel(const float* __restrict__ points,
                                  const float* __restrict__ feats,
                                  const float* __restrict__ camR,
                                  const float* __restrict__ camT,
                                  const float* __restrict__ fptr,
                                  int* __restrict__ counts,
                                  float4* __restrict__ lists,
                                  float* __restrict__ out,
                                  int B, int P)
{
    cg::grid_group grid = cg::this_grid();
    const int tid  = blockIdx.x * blockDim.x + threadIdx.x;
    const int npix = B * HWC;           // 32768 == grid size

    // ---- phase 1: zero candidate counts ----
    if (tid < npix) counts[tid] = 0;
    grid.sync();

    // ---- phase 2: project + scatter (one thread per point) ----
    if (tid < B * P) {
        const int b = tid / P;
        const int p = tid - b * P;
        const float* pp = points + (size_t)tid * 3;
        float p0 = pp[0], p1 = pp[1], p2 = pp[2];
        const float* R = camR + 9 * b;
        const float* t = camT + 3 * b;
        // row-vector convention: cam_j = sum_i p_i * R[i][j] + t[j]
        float x = p0*R[0] + p1*R[3] + p2*R[6] + t[0];
        float y = p0*R[1] + p1*R[4] + p2*R[7] + t[1];
        float z = p0*R[2] + p1*R[5] + p2*R[8] + t[2];
        float f = fptr[0];
        // exact numpy-match: (f*x)/z + cx, no contraction
        float px = __fadd_rn(__fdiv_rn(__fmul_rn(f, x), z), 64.0f);
        float py = __fadd_rn(__fdiv_rn(__fmul_rn(f, y), z), 64.0f);
        // unique candidate pixel: nearest center is floor (NaN-safe compares)
        float fx = floorf(px), fy = floorf(py);
        if (fx >= 0.0f && fx <= 127.0f && fy >= 0.0f && fy <= 127.0f) {
            int col = (int)fx, row = (int)fy;
            float gx = col + 0.5f, gy = row + 0.5f;
            // identical arithmetic to the reference's hit test
            float dx = __fmul_rn(__fsub_rn(px, gx), SCALE);
            float dy = __fmul_rn(__fsub_rn(py, gy), SCALE);
            float d2 = __fadd_rn(__fmul_rn(dx, dx), __fmul_rn(dy, dy));
            if (d2 < R2C && z > 1e-3f) {
                int pixel = b * HWC + row * IMGC + col;
                int slot  = atomicAdd(&counts[pixel], 1);   // device-scope by default
                if (slot < CAP)
                    lists[(size_t)pixel * CAP + slot] =
                        make_float4(z, d2, __int_as_float(p), 0.0f);
            }
        }
    }
    grid.sync();

    // ---- phase 3: composite (one thread per pixel) ----
    if (tid < npix) {
        const int b = tid / HWC;
        // agent-scope atomic load: bypass possibly-stale L1 line from phase 1
        int cnt = __hip_atomic_load(&counts[tid], __ATOMIC_RELAXED,
                                    __HIP_MEMORY_SCOPE_AGENT);
        if (cnt > CAP) cnt = CAP;

        float zk[KTOP], d2k[KTOP];
        int   ik[KTOP];
#pragma unroll
        for (int j = 0; j < KTOP; ++j) { zk[j] = BIGF; d2k[j] = 0.0f; ik[j] = 0x7fffffff; }

        for (int j = 0; j < cnt; ++j) {
            float4 v = lists[(size_t)tid * CAP + j];   // {z, d2, idx_bits}
            float vz = v.x;
            int   pi = __float_as_int(v.z);
            // lexicographic (z, idx) insertion == stable top_k selection
            if (vz < zk[KTOP-1] || (vz == zk[KTOP-1] && pi < ik[KTOP-1])) {
                zk[KTOP-1] = vz; d2k[KTOP-1] = v.y; ik[KTOP-1] = pi;
#pragma unroll
                for (int q = KTOP-1; q > 0; --q) {     // unrolled: compile-time indices
                    bool sw = (zk[q] < zk[q-1]) ||
                              (zk[q] == zk[q-1] && ik[q] < ik[q-1]);
                    if (sw) {
                        float tz = zk[q];  zk[q]  = zk[q-1];  zk[q-1]  = tz;
                        float td = d2k[q]; d2k[q] = d2k[q-1]; d2k[q-1] = td;
                        int   ti = ik[q];  ik[q]  = ik[q-1];  ik[q-1]  = ti;
                    }
                }
            }
        }

        // front-to-back alpha compositing: w_k = a_k * prod_{j<k}(1 - a_j)
        float T = 1.0f, c0 = 0.0f, c1 = 0.0f, c2 = 0.0f;
#pragma unroll
        for (int j = 0; j < KTOP; ++j) {
            if (zk[j] < 0.5f * BIGF) {
                float a = 1.0f - d2k[j] / R2C;
                a = fminf(fmaxf(a, 0.0f), 1.0f);
                float w = a * T;
                const float* ft = feats + ((size_t)b * P + ik[j]) * 3;
                c0 += w * ft[0]; c1 += w * ft[1]; c2 += w * ft[2];
                T *= (1.0f - a);
            }
        }

        float* img = out + (size_t)tid * 3;
        img[0] = c0; img[1] = c1; img[2] = c2;
        out[(size_t)B * HWC * 3 + tid] =
            (zk[0] < 0.5f * BIGF) ? zk[0] : -1.0f;
    }
}

// ---------- fallback 3-kernel path (used only if ws too small) ----------

__global__ void zero_counts_kernel(int* __restrict__ counts, int n)
{
    int i = blockIdx.x * blockDim.x + threadIdx.x;
    if (i < n) counts[i] = 0;
}

__global__ void proj_scatter_kernel(const float* __restrict__ points,
                                    const float* __restrict__ camR,
                                    const float* __restrict__ camT,
                                    const float* __restrict__ fptr,
                                    int* __restrict__ counts,
                                    float4* __restrict__ lists,
                                    int B, int P)
{
    int i = blockIdx.x * blockDim.x + threadIdx.x;
    if (i >= B * P) return;
    int b = i / P;
    int p = i - b * P;
    float p0 = points[3*i], p1 = points[3*i+1], p2 = points[3*i+2];
    const float* R = camR + 9*b;
    const float* t = camT + 3*b;
    float x = p0*R[0] + p1*R[3] + p2*R[6] + t[0];
    float y = p0*R[1] + p1*R[4] + p2*R[7] + t[1];
    float z = p0*R[2] + p1*R[5] + p2*R[8] + t[2];
    float f = fptr[0];
    float px = __fadd_rn(__fdiv_rn(__fmul_rn(f, x), z), 64.0f);
    float py = __fadd_rn(__fdiv_rn(__fmul_rn(f, y), z), 64.0f);
    float fx = floorf(px), fy = floorf(py);
    if (!(fx >= 0.0f && fx <= 127.0f && fy >= 0.0f && fy <= 127.0f)) return;
    int col = (int)fx, row = (int)fy;
    float gx = col + 0.5f, gy = row + 0.5f;
    float dx = __fmul_rn(__fsub_rn(px, gx), SCALE);
    float dy = __fmul_rn(__fsub_rn(py, gy), SCALE);
    float d2 = __fadd_rn(__fmul_rn(dx, dx), __fmul_rn(dy, dy));
    if (d2 < R2C && z > 1e-3f) {
        int pixel = b * HWC + row * IMGC + col;
        int slot  = atomicAdd(&counts[pixel], 1);
        if (slot < CAP)
            lists[(size_t)pixel * CAP + slot] = make_float4(z, d2, __int_as_float(p), 0.0f);
    }
}

__global__ void composite_kernel(const int* __restrict__ counts,
                                 const float4* __restrict__ lists,
                                 const float* __restrict__ feats,
                                 float* __restrict__ out,
                                 int B, int P)
{
    int t = blockIdx.x * blockDim.x + threadIdx.x;
    if (t >= B * HWC) return;
    int b = t / HWC;
    int cnt = counts[t];
    if (cnt > CAP) cnt = CAP;

    float zk[KTOP], d2k[KTOP];
    int   ik[KTOP];
#pragma unroll
    for (int j = 0; j < KTOP; ++j) { zk[j] = BIGF; d2k[j] = 0.0f; ik[j] = 0x7fffffff; }

    for (int j = 0; j < cnt; ++j) {
        float4 v = lists[(size_t)t * CAP + j];
        float vz = v.x;
        int   pi = __float_as_int(v.z);
        if (vz < zk[KTOP-1] || (vz == zk[KTOP-1] && pi < ik[KTOP-1])) {
            zk[KTOP-1] = vz; d2k[KTOP-1] = v.y; ik[KTOP-1] = pi;
#pragma unroll
            for (int q = KTOP-1; q > 0; --q) {
                bool sw = (zk[q] < zk[q-1]) ||
                          (zk[q] == zk[q-1] && ik[q] < ik[q-1]);
                if (sw) {
                    float tz = zk[q];  zk[q]  = zk[q-1];  zk[q-1]  = tz;
                    float td = d2k[q]; d2k[q] = d2k[q-1]; d2k[q-1] = td;
                    int   ti = ik[q];  ik[q]  = ik[q-1];  ik[q-1]  = ti;
                }
            }
        }
    }

    float T = 1.0f, c0 = 0.0f, c1 = 0.0f, c2 = 0.0f;
#pragma unroll
    for (int j = 0; j < KTOP; ++j) {
        if (zk[j] < 0.5f * BIGF) {
            float a = 1.0f - d2k[j] / R2C;
            a = fminf(fmaxf(a, 0.0f), 1.0f);
            float w = a * T;
            const float* ft = feats + ((size_t)b * P + ik[j]) * 3;
            c0 += w * ft[0]; c1 += w * ft[1]; c2 += w * ft[2];
            T *= (1.0f - a);
        }
    }

    float* img = out + (size_t)t * 3;
    img[0] = c0; img[1] = c1; img[2] = c2;
    out[(size_t)B * HWC * 3 + t] = (zk[0] < 0.5f * BIGF) ? zk[0] : -1.0f;
}

extern "C" void kernel_launch(void* const* d_in, const int* in_sizes, int n_in,
                              void* d_out, int out_size, void* d_ws, size_t ws_size,
                              hipStream_t stream) {
    const float* points = (const float*)d_in[0];
    const float* feats  = (const float*)d_in[1];
    const float* camR   = (const float*)d_in[2];
    const float* camT   = (const float*)d_in[3];
    const float* fptr   = (const float*)d_in[4];

    int B = in_sizes[3] / 3;        // cam_t is [B,3]
    int P = in_sizes[0] / (3 * B);  // points is [B,P,3]
    const int np   = B * P;
    const int npix = B * HWC;

    // workspace layout: counts (npix ints), lists (npix*CAP float4)
    size_t off_counts = 0;
    size_t off_lists  = (off_counts + (size_t)npix * sizeof(int) + 255) & ~(size_t)255;
    size_t needed     = off_lists + (size_t)npix * CAP * sizeof(float4);

    int*    counts = (int*)((char*)d_ws + off_counts);
    float4* lists  = (float4*)((char*)d_ws + off_lists);
    float*  out    = (float*)d_out;

    if (ws_size >= needed) {
        void* args[] = {(void*)&points, (void*)&feats, (void*)&camR, (void*)&camT,
                        (void*)&fptr, (void*)&counts, (void*)&lists, (void*)&out,
                        (void*)&B, (void*)&P};
        hipLaunchCooperativeKernel((const void*)fused_coop_kernel,
                                   dim3(npix / 256), dim3(256), args, 0, stream);
    } else {
        zero_counts_kernel<<<(npix + 255) / 256, 256, 0, stream>>>(counts, npix);
        proj_scatter_kernel<<<(np + 255) / 256, 256, 0, stream>>>(
            points, camR, camT, fptr, counts, lists, B, P);
        composite_kernel<<<(npix + 255) / 256, 256, 0, stream>>>(
            counts, lists, feats, out, B, P);
    }
}

// Round 5
// 98.148 us; speedup vs baseline: 1.1474x; 1.1474x over previous
//
#include <hip/hip_runtime.h>

// PointCloudRenderer — ONE regular launch, zero workspace.
// RADIUS=0.005 NDC = 0.32 px < 0.5 px => each point covers AT MOST ONE pixel
// center (validated rounds 2-4, absmax 0.0). One block per 8-row band
// (grid = B*16): project all P points (8/thread), append in-band hits to
// per-row LDS buckets, then each thread composites 4 pixels of one row by
// scanning its row bucket with lexicographic (z, point_idx) insertion —
// reproducing top_k's deterministic tie-break regardless of LDS-atomic
// arrival order. No d_ws use, no grid sync, no global round-trips.

constexpr int   IMGC  = 128;
constexpr int   HWC   = IMGC * IMGC;
constexpr int   KTOP  = 10;
constexpr int   ROWS  = 8;             // rows per block
constexpr int   CAPR  = 96;            // bucket cap per row (observed max ~25, mean ~10)
constexpr int   TPB   = 256;
constexpr float BIGF  = 1e10f;
constexpr float R2C   = 2.5e-05f;      // float32(0.005^2)
constexpr float SCALE = 0.015625f;     // 2/128, exact power of two

__launch_bounds__(TPB)
__global__ void render_band_kernel(const float* __restrict__ points,
                                   const float* __restrict__ feats,
                                   const float* __restrict__ camR,
                                   const float* __restrict__ camT,
                                   const float* __restrict__ fptr,
                                   float* __restrict__ out,
                                   int B, int P)
{
    __shared__ float4 bucket[ROWS][CAPR];  // {z, d2, idx_bits, col_bits}
    __shared__ int    cntRow[ROWS];

    const int b    = blockIdx.x >> 4;      // 16 bands per batch
    const int band = blockIdx.x & 15;
    const int r0   = band * ROWS;

    if (threadIdx.x < ROWS) cntRow[threadIdx.x] = 0;
    __syncthreads();

    const float* R = camR + 9 * b;
    const float* t = camT + 3 * b;
    const float  f = fptr[0];
    const float R00=R[0],R01=R[1],R02=R[2],
                R10=R[3],R11=R[4],R12=R[5],
                R20=R[6],R21=R[7],R22=R[8];
    const float t0=t[0], t1=t[1], t2=t[2];

    // ---- scatter phase: project all P points, keep hits in my 8-row band ----
    for (int p = threadIdx.x; p < P; p += TPB) {
        const float* pp = points + ((size_t)b * P + p) * 3;
        float p0 = pp[0], p1 = pp[1], p2 = pp[2];
        // row-vector convention: cam_j = sum_i p_i * R[i][j] + t[j]
        float x = p0*R00 + p1*R10 + p2*R20 + t0;
        float y = p0*R01 + p1*R11 + p2*R21 + t1;
        float z = p0*R02 + p1*R12 + p2*R22 + t2;
        // exact numpy-match: (f*x)/z + cx, no contraction
        float px = __fadd_rn(__fdiv_rn(__fmul_rn(f, x), z), 64.0f);
        float py = __fadd_rn(__fdiv_rn(__fmul_rn(f, y), z), 64.0f);
        // unique candidate pixel = floor (NaN-safe: compares false)
        float fx = floorf(px), fy = floorf(py);
        if (!(fx >= 0.0f && fx <= 127.0f &&
              fy >= (float)r0 && fy < (float)(r0 + ROWS))) continue;
        int col = (int)fx;
        float gx = fx + 0.5f, gy = fy + 0.5f;
        // identical arithmetic to the reference's hit test
        float dx = __fmul_rn(__fsub_rn(px, gx), SCALE);
        float dy = __fmul_rn(__fsub_rn(py, gy), SCALE);
        float d2 = __fadd_rn(__fmul_rn(dx, dx), __fmul_rn(dy, dy));
        if (d2 < R2C && z > 1e-3f) {
            int r = (int)fy - r0;
            int s = atomicAdd(&cntRow[r], 1);
            if (s < CAPR)
                bucket[r][s] = make_float4(z, d2, __int_as_float(p),
                                           __int_as_float(col));
        }
    }
    __syncthreads();

    // ---- composite phase: thread -> one row, 4 consecutive pixels ----
    const int lrow = threadIdx.x >> 5;          // 0..7
    const int row  = r0 + lrow;
    const int cbase = (threadIdx.x & 31) * 4;   // 0,4,...,124
    int cnt = cntRow[lrow];
    if (cnt > CAPR) cnt = CAPR;

    for (int c = cbase; c < cbase + 4; ++c) {
        float zk[KTOP], d2k[KTOP];
        int   ik[KTOP];
#pragma unroll
        for (int j = 0; j < KTOP; ++j) { zk[j] = BIGF; d2k[j] = 0.0f; ik[j] = 0x7fffffff; }

        for (int j = 0; j < cnt; ++j) {
            float4 v = bucket[lrow][j];         // half-wave broadcast LDS read
            if (__float_as_int(v.w) != c) continue;
            float vz = v.x;
            int   pi = __float_as_int(v.z);
            // lexicographic (z, idx) insertion == stable top_k selection
            if (vz < zk[KTOP-1] || (vz == zk[KTOP-1] && pi < ik[KTOP-1])) {
                zk[KTOP-1] = vz; d2k[KTOP-1] = v.y; ik[KTOP-1] = pi;
#pragma unroll
                for (int q = KTOP-1; q > 0; --q) {   // unrolled: compile-time idx
                    bool sw = (zk[q] < zk[q-1]) ||
                              (zk[q] == zk[q-1] && ik[q] < ik[q-1]);
                    if (sw) {
                        float tz = zk[q];  zk[q]  = zk[q-1];  zk[q-1]  = tz;
                        float td = d2k[q]; d2k[q] = d2k[q-1]; d2k[q-1] = td;
                        int   ti = ik[q];  ik[q]  = ik[q-1];  ik[q-1]  = ti;
                    }
                }
            }
        }

        // front-to-back alpha compositing: w_k = a_k * prod_{j<k}(1 - a_j)
        float T = 1.0f, c0f = 0.0f, c1f = 0.0f, c2f = 0.0f;
#pragma unroll
        for (int j = 0; j < KTOP; ++j) {
            if (zk[j] < 0.5f * BIGF) {
                float a = 1.0f - d2k[j] / R2C;
                a = fminf(fmaxf(a, 0.0f), 1.0f);
                float w = a * T;
                const float* ft = feats + ((size_t)b * P + ik[j]) * 3;
                c0f += w * ft[0]; c1f += w * ft[1]; c2f += w * ft[2];
                T *= (1.0f - a);
            }
        }

        const int pix = row * IMGC + c;
        float* img = out + (size_t)(b * HWC + pix) * 3;
        img[0] = c0f; img[1] = c1f; img[2] = c2f;
        // depth image: nearest z or -1 background
        out[(size_t)B * HWC * 3 + (size_t)b * HWC + pix] =
            (zk[0] < 0.5f * BIGF) ? zk[0] : -1.0f;
    }
}

extern "C" void kernel_launch(void* const* d_in, const int* in_sizes, int n_in,
                              void* d_out, int out_size, void* d_ws, size_t ws_size,
                              hipStream_t stream) {
    const float* points = (const float*)d_in[0];
    const float* feats  = (const float*)d_in[1];
    const float* camR   = (const float*)d_in[2];
    const float* camT   = (const float*)d_in[3];
    const float* fptr   = (const float*)d_in[4];

    const int B = in_sizes[3] / 3;        // cam_t is [B,3]
    const int P = in_sizes[0] / (3 * B);  // points is [B,P,3]

    render_band_kernel<<<B * 16, TPB, 0, stream>>>(
        points, feats, camR, camT, fptr, (float*)d_out, B, P);
}

// Round 6
// 72.400 us; speedup vs baseline: 1.5554x; 1.3557x over previous
//
#include <hip/hip_runtime.h>

// PointCloudRenderer — ONE launch, zero workspace, spill-proof K-list.
// RADIUS=0.005 NDC = 0.32 px < 0.5 px => each point covers AT MOST ONE pixel
// center (validated rounds 2-5, absmax 0.0). One block per image row
// (grid = B*128): project all P points (8/thread), append in-row hits to an
// LDS bucket, then lanes 0..127 each composite one pixel by scanning the
// bucket. The K=10 z-list lives in 30 NAMED scalar registers (no arrays ->
// nothing can be demoted to scratch; round-5's 45us kernel was exactly that
// spill: VGPR_Count=32 + 1% VALUBusy). Lexicographic (z, point_idx) ordering
// reproduces top_k's deterministic tie-break regardless of LDS-atomic
// arrival order.

constexpr int   IMGC  = 128;
constexpr int   HWC   = IMGC * IMGC;
constexpr int   CAPR  = 128;           // bucket cap per row (observed max ~25)
constexpr int   TPB   = 256;
constexpr float BIGF  = 1e10f;
constexpr float R2C   = 2.5e-05f;      // float32(0.005^2)
constexpr float SCALE = 0.015625f;     // 2/128, exact power of two

// lexicographic compare-swap of two named slots: (zb,ib) moves up if smaller
#define CSWAP(za, da, ia, zb, db, ib)                                  \
    {                                                                  \
        bool sw_ = (zb < za) || (zb == za && ib < ia);                 \
        float tz_ = za, td_ = da; int ti_ = ia;                        \
        if (sw_) { za = zb; da = db; ia = ib;                          \
                   zb = tz_; db = td_; ib = ti_; }                     \
    }

#define COMPOSE(zq, dq, iq)                                            \
    if (zq < 0.5f * BIGF) {                                            \
        float a_ = 1.0f - dq / R2C;                                    \
        a_ = fminf(fmaxf(a_, 0.0f), 1.0f);                             \
        float w_ = a_ * T;                                             \
        const float* ft_ = feats + ((size_t)b * P + iq) * 3;           \
        cr += w_ * ft_[0]; cg += w_ * ft_[1]; cb += w_ * ft_[2];       \
        T *= (1.0f - a_);                                              \
    }

__launch_bounds__(TPB)
__global__ void render_row_kernel(const float* __restrict__ points,
                                  const float* __restrict__ feats,
                                  const float* __restrict__ camR,
                                  const float* __restrict__ camT,
                                  const float* __restrict__ fptr,
                                  float* __restrict__ out,
                                  int B, int P)
{
    __shared__ float4 bucket[CAPR];    // {z, d2, idx_bits, col_bits}
    __shared__ int    cnt;

    const int b   = blockIdx.x >> 7;   // 128 rows per batch image
    const int row = blockIdx.x & 127;

    if (threadIdx.x == 0) cnt = 0;
    __syncthreads();

    const float* R = camR + 9 * b;
    const float* t = camT + 3 * b;
    const float  f = fptr[0];
    const float R00=R[0],R01=R[1],R02=R[2],
                R10=R[3],R11=R[4],R12=R[5],
                R20=R[6],R21=R[7],R22=R[8];
    const float t0=t[0], t1=t[1], t2=t[2];
    const float rowF = (float)row;

    // ---- scatter: project all P points, keep hits landing in my row ----
    for (int p = threadIdx.x; p < P; p += TPB) {
        const float* pp = points + ((size_t)b * P + p) * 3;
        float p0 = pp[0], p1 = pp[1], p2 = pp[2];
        // row-vector convention: cam_j = sum_i p_i * R[i][j] + t[j]
        float x = p0*R00 + p1*R10 + p2*R20 + t0;
        float y = p0*R01 + p1*R11 + p2*R21 + t1;
        float z = p0*R02 + p1*R12 + p2*R22 + t2;
        // exact numpy-match: (f*x)/z + cx, no contraction
        float px = __fadd_rn(__fdiv_rn(__fmul_rn(f, x), z), 64.0f);
        float py = __fadd_rn(__fdiv_rn(__fmul_rn(f, y), z), 64.0f);
        // unique candidate pixel = floor (NaN-safe: compares false)
        float fx = floorf(px), fy = floorf(py);
        if (!(fx >= 0.0f && fx <= 127.0f && fy == rowF)) continue;
        float gx = fx + 0.5f, gy = fy + 0.5f;
        // identical arithmetic to the reference's hit test
        float dx = __fmul_rn(__fsub_rn(px, gx), SCALE);
        float dy = __fmul_rn(__fsub_rn(py, gy), SCALE);
        float d2 = __fadd_rn(__fmul_rn(dx, dx), __fmul_rn(dy, dy));
        if (d2 < R2C && z > 1e-3f) {
            int s = atomicAdd(&cnt, 1);
            if (s < CAPR)
                bucket[s] = make_float4(z, d2, __int_as_float(p),
                                        __int_as_float((int)fx));
        }
    }
    __syncthreads();
    int n = cnt; if (n > CAPR) n = CAPR;

    // ---- composite: lanes 0..127 -> one pixel each ----
    if (threadIdx.x < IMGC) {
        const int col = threadIdx.x;

        // K=10 list in NAMED registers, sorted lex ascending by (z, idx)
        float z0=BIGF,z1=BIGF,z2=BIGF,z3=BIGF,z4=BIGF,
              z5=BIGF,z6=BIGF,z7=BIGF,z8=BIGF,z9=BIGF;
        float d0=0,d1=0,d2_=0,d3=0,d4=0,d5=0,d6=0,d7=0,d8=0,d9=0;
        int   i0=0x7fffffff,i1=0x7fffffff,i2=0x7fffffff,i3=0x7fffffff,
              i4=0x7fffffff,i5=0x7fffffff,i6=0x7fffffff,i7=0x7fffffff,
              i8=0x7fffffff,i9=0x7fffffff;

        for (int j = 0; j < n; ++j) {
            float4 v = bucket[j];      // wave-uniform LDS broadcast
            if (__float_as_int(v.w) != col) continue;
            float vz = v.x, vd = v.y;
            int   vi = __float_as_int(v.z);
            if (vz < z9 || (vz == z9 && vi < i9)) {
                z9 = vz; d9 = vd; i9 = vi;
                CSWAP(z8, d8, i8, z9, d9, i9);
                CSWAP(z7, d7, i7, z8, d8, i8);
                CSWAP(z6, d6, i6, z7, d7, i7);
                CSWAP(z5, d5, i5, z6, d6, i6);
                CSWAP(z4, d4, i4, z5, d5, i5);
                CSWAP(z3, d3, i3, z4, d4, i4);
                CSWAP(z2, d2_, i2, z3, d3, i3);
                CSWAP(z1, d1, i1, z2, d2_, i2);
                CSWAP(z0, d0, i0, z1, d1, i1);
            }
        }

        // front-to-back alpha compositing: w_k = a_k * prod_{j<k}(1 - a_j)
        float T = 1.0f, cr = 0.0f, cg = 0.0f, cb = 0.0f;
        COMPOSE(z0, d0, i0)
        COMPOSE(z1, d1, i1)
        COMPOSE(z2, d2_, i2)
        COMPOSE(z3, d3, i3)
        COMPOSE(z4, d4, i4)
        COMPOSE(z5, d5, i5)
        COMPOSE(z6, d6, i6)
        COMPOSE(z7, d7, i7)
        COMPOSE(z8, d8, i8)
        COMPOSE(z9, d9, i9)

        const int pix = row * IMGC + col;
        float* img = out + (size_t)(b * HWC + pix) * 3;
        img[0] = cr; img[1] = cg; img[2] = cb;
        // depth image: nearest z or -1 background
        out[(size_t)B * HWC * 3 + (size_t)b * HWC + pix] =
            (z0 < 0.5f * BIGF) ? z0 : -1.0f;
    }
}

extern "C" void kernel_launch(void* const* d_in, const int* in_sizes, int n_in,
                              void* d_out, int out_size, void* d_ws, size_t ws_size,
                              hipStream_t stream) {
    const float* points = (const float*)d_in[0];
    const float* feats  = (const float*)d_in[1];
    const float* camR   = (const float*)d_in[2];
    const float* camT   = (const float*)d_in[3];
    const float* fptr   = (const float*)d_in[4];

    const int B = in_sizes[3] / 3;        // cam_t is [B,3]
    const int P = in_sizes[0] / (3 * B);  // points is [B,P,3]

    render_row_kernel<<<B * IMGC, TPB, 0, stream>>>(
        points, feats, camR, camT, fptr, (float*)d_out, B, P);
}